// Round 3
// baseline (109.081 us; speedup 1.0000x reference)
//
#include <hip/hip_runtime.h>
#include <hip/hip_cooperative_groups.h>
#include <math.h>

namespace cg = cooperative_groups;

#define BROWS 8192
#define F 10
#define NT 16                   // tiles; wave w's tile t = j-block t*16+w (32 j-rows)
#define NW 16                   // waves per block (1024 threads)
#define IB 32                   // i-rows per block (two 16-row MFMA groups)
#define PR 32                   // fused phase-1: pooled rows per block
#define SQRT_LOG2E 1.2011224087864498f   // q prescaled so a1*b1 carries log2e once

#if __has_builtin(__builtin_amdgcn_exp2f)
#define EXP2F(x) __builtin_amdgcn_exp2f(x)
#else
#define EXP2F(x) exp2f(x)
#endif

// s_waitcnt imm: vmcnt[3:0] | expcnt(7, no-wait)<<4 | lgkmcnt(15, no-wait)<<8
#define WAITVM(n) __builtin_amdgcn_s_waitcnt(0xF00 | 0x70 | (n))

typedef _Float16 half4 __attribute__((ext_vector_type(4)));
typedef __fp16 fp16x2 __attribute__((ext_vector_type(2)));
typedef float floatx4 __attribute__((ext_vector_type(4)));

__device__ __forceinline__ half4 exp4_to_h4(float a, float b, float c, float d) {
#if __has_builtin(__builtin_amdgcn_cvt_pkrtz)
    union { fp16x2 h2[2]; half4 h4; } u;
    u.h2[0] = __builtin_amdgcn_cvt_pkrtz(EXP2F(a), EXP2F(b));
    u.h2[1] = __builtin_amdgcn_cvt_pkrtz(EXP2F(c), EXP2F(d));
    return u.h4;
#else
    half4 r;
    r[0] = (_Float16)EXP2F(a); r[1] = (_Float16)EXP2F(b);
    r[2] = (_Float16)EXP2F(c); r[3] = (_Float16)EXP2F(d);
    return r;
#endif
}

// async global->LDS DMA, 16B/lane; lds addr = wave-uniform base + lane*16.
__device__ __forceinline__ void gload_lds16(const void* g, void* l) {
#if __has_builtin(__builtin_amdgcn_global_load_lds)
    __builtin_amdgcn_global_load_lds(
        (const __attribute__((address_space(1))) void*)g,
        (__attribute__((address_space(3))) void*)l, 16, 0, 0);
#else
    *(float4*)l = *(const float4*)g;
#endif
}

// ---------------------------------------------------------------------------
// FUSED kernel (cooperative): phase 1 = pooled projection (writes the two
// R14-proven layouts to workspace), grid.sync(), phase 2 = MFMA flash attn
// with wave-private depth-4 ring, graduated vmcnt waits, zero K-loop
// barriers (body identical to R2's verified attn_kernel).
//
// Grid: 256 blocks x 1024 threads, 128 KB LDS -> exactly 1 block/CU on 256
// CUs, so cooperative co-residency holds. Fusion removes one full-device
// launch + the inter-kernel dependency gap from the captured graph; the
// grid sync provides the cross-XCD release/acquire the kernel boundary
// used to provide.
//
// Layouts (correctness-proven):
//   q_tiled[b][0..15]: feats 0..9 scaled by sqrt(log2e), 10..15 = 0.
//   a_tiled[jblk][o][32]: rows 0..9 = pooled^T, row 10 = ONES, 11..15 = 0.
// ---------------------------------------------------------------------------
__global__ void fused_kernel(const float* __restrict__ x,
                             const float* __restrict__ A,
                             const float* __restrict__ W,
                             _Float16* __restrict__ q_tiled,
                             _Float16* __restrict__ a_tiled,
                             float* __restrict__ out) {
    __shared__ __align__(16) _Float16 ring[4][NW][1024];   // 4 x 16 x 2 KB = 128 KB
    float* red = (float*)&ring[0][0][0];                   // aliases ring (phase-gated)

    const int tid = threadIdx.x;

    // ---------------- phase 1: pooled (32 rows x 16 cols per block) --------
    {
        float* xs = (float*)&ring[0][0][0];                // 960 floats = 3840 B
        const int b0 = blockIdx.x * PR;

        // stage x: 960 floats = 480 float2, fully coalesced
        if (tid < 480) {
            float2 t = ((const float2*)(x + (size_t)b0 * 30))[tid];
            xs[2 * tid] = t.x;
            xs[2 * tid + 1] = t.y;
        }
        __syncthreads();

        if (tid < PR * 16) {
            const int r = tid >> 4;         // 0..31 row within block
            const int o = tid & 15;         // 0..15 output column
            const int b = b0 + r;

            const float c0 = 0.125f * (1.0f + A[0] + A[3]);
            const float c1 = 0.125f * (1.0f + A[1] + A[4]);
            const float c2 = 0.125f * (2.0f + A[2] + A[5]);

            float po = 0.0f;
            if (o < F) {
                const float* xr = &xs[r * 30];
#pragma unroll
                for (int f = 0; f < F; ++f) {
                    float y = c0 * xr[f] + c1 * xr[F + f] + c2 * xr[2 * F + f];
                    po = fmaf(y, W[f * F + o], po);  // 16 lanes share addr -> broadcast
                }
            }

            q_tiled[(size_t)b * 16 + o] =
                (o < F) ? (_Float16)(SQRT_LOG2E * po) : (_Float16)0.0f;

            _Float16 av = (o < F) ? (_Float16)po
                                  : (o == F ? (_Float16)1.0f : (_Float16)0.0f);
            a_tiled[(size_t)(b >> 5) * 512 + o * 32 + (b & 31)] = av;
        }
    }

    // ---------------- grid-wide sync (all q/a visible device-wide) --------
    cg::this_grid().sync();

    // ---------------- phase 2: attn (verified R2 body) ---------------------
    const int wave = tid >> 6;          // 0..15
    const int lane = tid & 63;
    const int m    = lane & 15;
    const int quad = lane >> 4;
    const int i0   = blockIdx.x * IB;
    const int lofs = lane * 16;

    // B1 fragments for the two i-groups (q_tiled prescaled; cols 10..15 zero)
    half4 b1a = *(const half4*)(q_tiled + (size_t)(i0 + m) * 16 + quad * 4);
    half4 b1b = *(const half4*)(q_tiled + (size_t)(i0 + 16 + m) * 16 + quad * 4);

    // rolling private DMA sources: j-block g = t*16 + wave, 16 KB/tile stride
    const char* qsrc = (const char*)q_tiled + (size_t)wave * 1024 + lofs;
    const char* asrc = (const char*)a_tiled + (size_t)wave * 1024 + lofs;

    // prologue: stage tiles 0..2 into slots 0..2 (q at +0, a at +1024 B)
#pragma unroll
    for (int s = 0; s < 3; ++s) {
        char* dst = (char*)&ring[s][wave][0] + lofs;
        gload_lds16(qsrc, dst);
        gload_lds16(asrc, dst + 1024);
        qsrc += 16 * 1024; asrc += 16 * 1024;
    }

    floatx4 accA0 = {0.f,0.f,0.f,0.f}, accA1 = {0.f,0.f,0.f,0.f};
    floatx4 accB0 = {0.f,0.f,0.f,0.f}, accB1 = {0.f,0.f,0.f,0.f};

#pragma unroll
    for (int t = 0; t < NT; ++t) {
        // graduated wait: drain only the oldest slot's 2 loads
        if (t < NT - 2)      WAITVM(4);
        else if (t == NT-2)  WAITVM(2);
        else                 WAITVM(0);

        const _Float16* qs  = &ring[t & 3][wave][0];
        const _Float16* as_ = qs + 512;
        half4 a1_0 = *(const half4*)&qs[(0 * 16 + m) * 16 + quad * 4];
        half4 a1_1 = *(const half4*)&qs[(1 * 16 + m) * 16 + quad * 4];
        half4 ag_0 = *(const half4*)&as_[m * 32 + 0 * 16 + quad * 4];
        half4 ag_1 = *(const half4*)&as_[m * 32 + 1 * 16 + quad * 4];

        if (t + 3 < NT) {   // prefetch 3 tiles ahead into the freed slot
            char* dst = (char*)&ring[(t + 3) & 3][wave][0] + lofs;
            gload_lds16(qsrc, dst);
            gload_lds16(asrc, dst + 1024);
            qsrc += 16 * 1024; asrc += 16 * 1024;
        }

        floatx4 z = {0.f,0.f,0.f,0.f};
        floatx4 d1a0 = __builtin_amdgcn_mfma_f32_16x16x16f16(a1_0, b1a, z, 0, 0, 0);
        floatx4 d1b0 = __builtin_amdgcn_mfma_f32_16x16x16f16(a1_0, b1b, z, 0, 0, 0);
        floatx4 d1a1 = __builtin_amdgcn_mfma_f32_16x16x16f16(a1_1, b1a, z, 0, 0, 0);
        floatx4 d1b1 = __builtin_amdgcn_mfma_f32_16x16x16f16(a1_1, b1b, z, 0, 0, 0);
        half4 a2a0 = exp4_to_h4(d1a0[0], d1a0[1], d1a0[2], d1a0[3]);
        half4 a2b0 = exp4_to_h4(d1b0[0], d1b0[1], d1b0[2], d1b0[3]);
        half4 a2a1 = exp4_to_h4(d1a1[0], d1a1[1], d1a1[2], d1a1[3]);
        half4 a2b1 = exp4_to_h4(d1b1[0], d1b1[1], d1b1[2], d1b1[3]);
        accA0 = __builtin_amdgcn_mfma_f32_16x16x16f16(ag_0, a2a0, accA0, 0, 0, 0);
        accB0 = __builtin_amdgcn_mfma_f32_16x16x16f16(ag_0, a2b0, accB0, 0, 0, 0);
        accA1 = __builtin_amdgcn_mfma_f32_16x16x16f16(ag_1, a2a1, accA1, 0, 0, 0);
        accB1 = __builtin_amdgcn_mfma_f32_16x16x16f16(ag_1, a2b1, accB1, 0, 0, 0);
    }

    floatx4 accA = accA0 + accA1;   // V^T[f=quad*4+r][i=i0+m],    f=10 -> l
    floatx4 accB = accB0 + accB1;   // V^T[f=quad*4+r][i=i0+16+m]

    __syncthreads();   // all waves done with ring (red aliases it)
    if (quad < 3) {
        *(floatx4*)&red[((size_t)wave * IB + m) * 12 + quad * 4] = accA;
        *(floatx4*)&red[((size_t)wave * IB + 16 + m) * 12 + quad * 4] = accB;
    }
    __syncthreads();

    if (tid < IB * F) {
        const int i = tid / F;      // 0..31
        const int f = tid % F;
        float sum = 0.0f, l = 0.0f;
#pragma unroll
        for (int w = 0; w < NW; ++w) {
            sum += red[((size_t)w * IB + i) * 12 + f];
            l   += red[((size_t)w * IB + i) * 12 + 10];
        }
        out[(size_t)(i0 + i) * F + f] = sum / l;
    }
}

// ---------------------------------------------------------------------------
extern "C" void kernel_launch(void* const* d_in, const int* in_sizes, int n_in,
                              void* d_out, int out_size, void* d_ws, size_t ws_size,
                              hipStream_t stream) {
    const float* x = (const float*)d_in[0];   // [8192,3,10]
    const float* A = (const float*)d_in[1];   // [3,3]
    const float* W = (const float*)d_in[2];   // [10,10]
    float* out = (float*)d_out;               // [8192,10]

    _Float16* q_tiled = (_Float16*)d_ws;                      // 8192*16*2 = 262144 B
    _Float16* a_tiled = (_Float16*)((char*)d_ws + 262144);    // 256*512*2 = 262144 B

    void* args[] = { (void*)&x, (void*)&A, (void*)&W,
                     (void*)&q_tiled, (void*)&a_tiled, (void*)&out };
    hipLaunchCooperativeKernel((const void*)fused_kernel,
                               dim3(BROWS / IB), dim3(NW * 64),
                               args, 0, stream);
}

// Round 4
// 68.128 us; speedup vs baseline: 1.6011x; 1.6011x over previous
//
#include <hip/hip_runtime.h>
#include <math.h>

#define BROWS 8192
#define F 10
#define NT 16                   // tiles; wave w's tile t = j-block t*16+w (32 j-rows)
#define NW 16                   // waves per block (1024 threads)
#define IB 32                   // i-rows per block (two 16-row MFMA groups)
#define PB 16                   // pooled: rows per block (256 threads = 16 rows x 16 cols)
#define SQRT_LOG2E 1.2011224087864498f   // q prescaled so a1*b1 carries log2e once

#if __has_builtin(__builtin_amdgcn_exp2f)
#define EXP2F(x) __builtin_amdgcn_exp2f(x)
#else
#define EXP2F(x) exp2f(x)
#endif

// s_waitcnt imm: vmcnt[3:0] | expcnt(7, no-wait)<<4 | lgkmcnt(15, no-wait)<<8
#define WAITVM(n) __builtin_amdgcn_s_waitcnt(0xF00 | 0x70 | (n))

typedef _Float16 half4 __attribute__((ext_vector_type(4)));
typedef _Float16 half8 __attribute__((ext_vector_type(8)));
typedef __fp16 fp16x2 __attribute__((ext_vector_type(2)));
typedef float floatx4 __attribute__((ext_vector_type(4)));

__device__ __forceinline__ half4 exp4_to_h4(float a, float b, float c, float d) {
#if __has_builtin(__builtin_amdgcn_cvt_pkrtz)
    union { fp16x2 h2[2]; half4 h4; } u;
    u.h2[0] = __builtin_amdgcn_cvt_pkrtz(EXP2F(a), EXP2F(b));
    u.h2[1] = __builtin_amdgcn_cvt_pkrtz(EXP2F(c), EXP2F(d));
    return u.h4;
#else
    half4 r;
    r[0] = (_Float16)EXP2F(a); r[1] = (_Float16)EXP2F(b);
    r[2] = (_Float16)EXP2F(c); r[3] = (_Float16)EXP2F(d);
    return r;
#endif
}

// async global->LDS DMA, 16B/lane; lds addr = wave-uniform base + lane*16.
__device__ __forceinline__ void gload_lds16(const void* g, void* l) {
#if __has_builtin(__builtin_amdgcn_global_load_lds)
    __builtin_amdgcn_global_load_lds(
        (const __attribute__((address_space(1))) void*)g,
        (__attribute__((address_space(3))) void*)l, 16, 0, 0);
#else
    *(float4*)l = *(const float4*)g;
#endif
}

// ---------------------------------------------------------------------------
// Kernel 1 (v3): same grid as v2 (512 blocks x 256 thr, LDS-staged x), but
// the two output layouts are FRAGMENT-PAIRED so the attn kernel's per-tile
// LDS reads become single ds_read_b128 per operand:
//   q_tiled tile (32 rows x 16 f, 512 halfs): row j (m=j&15, g=j>>4),
//     feat f (q=f>>2, r=f&3) stored at m*32 + q*8 + g*4 + r.
//     Feats 0..9 scaled by sqrt(log2e), 10..15 = 0.
//   a_tiled tile: o (0..15; 0..9 pooled^T, 10 = ONES, 11..15 = 0),
//     col j (q=(j&15)>>2, g=j>>4, r=j&3) stored at o*32 + q*8 + g*4 + r.
// Fragment VALUES are bit-identical to the R2-proven scheme; only the
// placement changed so lane (m,quad)'s g=0/g=1 fragments are 16B adjacent.
// ---------------------------------------------------------------------------
__global__ void pooled_kernel(const float* __restrict__ x,
                              const float* __restrict__ A,
                              const float* __restrict__ W,
                              _Float16* __restrict__ q_tiled,
                              _Float16* __restrict__ a_tiled) {
    __shared__ float xs[PB * 30];           // 16 rows x 30 floats = 1920 B
    const int tid = threadIdx.x;            // 0..255
    const int b0 = blockIdx.x * PB;

    // stage x: 480 floats = 240 float2, fully coalesced
    if (tid < 240) {
        float2 t = ((const float2*)(x + (size_t)b0 * 30))[tid];
        xs[2 * tid] = t.x;
        xs[2 * tid + 1] = t.y;
    }
    __syncthreads();

    const int r = tid >> 4;                 // 0..15 row within block
    const int o = tid & 15;                 // 0..15 output column
    const int b = b0 + r;

    const float c0 = 0.125f * (1.0f + A[0] + A[3]);
    const float c1 = 0.125f * (1.0f + A[1] + A[4]);
    const float c2 = 0.125f * (2.0f + A[2] + A[5]);

    float po = 0.0f;
    if (o < F) {
        const float* xr = &xs[r * 30];
#pragma unroll
        for (int f = 0; f < F; ++f) {
            float y = c0 * xr[f] + c1 * xr[F + f] + c2 * xr[2 * F + f];
            po = fmaf(y, W[f * F + o], po);  // 16 lanes share addr -> broadcast
        }
    }

    const int jm = b & 15;                  // row-within-16
    const int jg = (b >> 4) & 1;            // 16-row group
    const size_t tbase = (size_t)(b >> 5) * 512;

    // q: row j=b, feat o -> m*32 + (o>>2)*8 + g*4 + (o&3)
    q_tiled[tbase + jm * 32 + (o >> 2) * 8 + jg * 4 + (o & 3)] =
        (o < F) ? (_Float16)(SQRT_LOG2E * po) : (_Float16)0.0f;

    // a: row o, col j=b -> o*32 + ((j&15)>>2)*8 + g*4 + (j&3)
    _Float16 av = (o < F) ? (_Float16)po
                          : (o == F ? (_Float16)1.0f : (_Float16)0.0f);
    a_tiled[tbase + o * 32 + (jm >> 2) * 8 + jg * 4 + (b & 3)] = av;
}

// ---------------------------------------------------------------------------
// Kernel 2 (v3): MFMA flash attention, wave-private DEPTH-4 ring, graduated
// vmcnt waits, ZERO K-loop barriers. vmcnt ring schedule IDENTICAL to the
// R2-verified kernel (sync structure frozen). Changes:
//   * fragment-paired tiles -> 2 ds_read_b128 per tile instead of 4
//     ds_read_b64 (kills the ag 8-way b64 conflict; b128 at the LDS floor)
//   * b1a/b1b from ONE 16B global load
//   * s_setprio(1) around the MFMA+exp cluster (independent waves -> the
//     m191-positive regime, not the m190 lockstep null)
// 256 blocks x 1024 thr, LDS 128 KB -> 1 block/CU, 4 waves/SIMD.
// ---------------------------------------------------------------------------
__global__ void attn_kernel(const _Float16* __restrict__ q_tiled,
                            const _Float16* __restrict__ a_tiled,
                            float* __restrict__ out) {
    __shared__ __align__(16) _Float16 ring[4][NW][1024];   // 4 x 16 x 2 KB = 128 KB
    float* red = (float*)&ring[0][0][0];                   // 24576 B, after final barrier

    const int tid  = threadIdx.x;
    const int wave = tid >> 6;          // 0..15
    const int lane = tid & 63;
    const int m    = lane & 15;
    const int quad = lane >> 4;
    const int i0   = blockIdx.x * IB;
    const int lofs = lane * 16;

    // B1 fragments, both i-groups in one 16B load (fragment-paired layout)
    union { half8 h8; half4 h4[2]; } ub;
    ub.h8 = *(const half8*)(q_tiled + (size_t)i0 * 16 + m * 32 + quad * 8);
    const half4 b1a = ub.h4[0];
    const half4 b1b = ub.h4[1];

    // rolling private DMA sources: j-block g = t*16 + wave, 16 KB/tile stride
    const char* qsrc = (const char*)q_tiled + (size_t)wave * 1024 + lofs;
    const char* asrc = (const char*)a_tiled + (size_t)wave * 1024 + lofs;

    // prologue: stage tiles 0..2 into slots 0..2 (q at +0, a at +1024 B)
#pragma unroll
    for (int s = 0; s < 3; ++s) {
        char* dst = (char*)&ring[s][wave][0] + lofs;
        gload_lds16(qsrc, dst);
        gload_lds16(asrc, dst + 1024);
        qsrc += 16 * 1024; asrc += 16 * 1024;
    }

    floatx4 accA0 = {0.f,0.f,0.f,0.f}, accA1 = {0.f,0.f,0.f,0.f};
    floatx4 accB0 = {0.f,0.f,0.f,0.f}, accB1 = {0.f,0.f,0.f,0.f};

#pragma unroll
    for (int t = 0; t < NT; ++t) {
        // graduated wait: drain only the oldest slot's 2 loads
        if (t < NT - 2)      WAITVM(4);
        else if (t == NT-2)  WAITVM(2);
        else                 WAITVM(0);

        const _Float16* qs = &ring[t & 3][wave][0];
        union { half8 h8; half4 h4[2]; } uq, ua;
        uq.h8 = *(const half8*)&qs[m * 32 + quad * 8];          // a1 pair
        ua.h8 = *(const half8*)&qs[512 + m * 32 + quad * 8];    // ag pair
        const half4 a1_0 = uq.h4[0], a1_1 = uq.h4[1];
        const half4 ag_0 = ua.h4[0], ag_1 = ua.h4[1];

        if (t + 3 < NT) {   // prefetch 3 tiles ahead into the freed slot
            char* dst = (char*)&ring[(t + 3) & 3][wave][0] + lofs;
            gload_lds16(qsrc, dst);
            gload_lds16(asrc, dst + 1024);
            qsrc += 16 * 1024; asrc += 16 * 1024;
        }

        __builtin_amdgcn_s_setprio(1);
        floatx4 z = {0.f,0.f,0.f,0.f};
        floatx4 d1a0 = __builtin_amdgcn_mfma_f32_16x16x16f16(a1_0, b1a, z, 0, 0, 0);
        floatx4 d1b0 = __builtin_amdgcn_mfma_f32_16x16x16f16(a1_0, b1b, z, 0, 0, 0);
        floatx4 d1a1 = __builtin_amdgcn_mfma_f32_16x16x16f16(a1_1, b1a, z, 0, 0, 0);
        floatx4 d1b1 = __builtin_amdgcn_mfma_f32_16x16x16f16(a1_1, b1b, z, 0, 0, 0);
        half4 a2a0 = exp4_to_h4(d1a0[0], d1a0[1], d1a0[2], d1a0[3]);
        half4 a2b0 = exp4_to_h4(d1b0[0], d1b0[1], d1b0[2], d1b0[3]);
        half4 a2a1 = exp4_to_h4(d1a1[0], d1a1[1], d1a1[2], d1a1[3]);
        half4 a2b1 = exp4_to_h4(d1b1[0], d1b1[1], d1b1[2], d1b1[3]);
        accA0 = __builtin_amdgcn_mfma_f32_16x16x16f16(ag_0, a2a0, accA0, 0, 0, 0);
        accB0 = __builtin_amdgcn_mfma_f32_16x16x16f16(ag_0, a2b0, accB0, 0, 0, 0);
        accA1 = __builtin_amdgcn_mfma_f32_16x16x16f16(ag_1, a2a1, accA1, 0, 0, 0);
        accB1 = __builtin_amdgcn_mfma_f32_16x16x16f16(ag_1, a2b1, accB1, 0, 0, 0);
        __builtin_amdgcn_s_setprio(0);
    }

    floatx4 accA = accA0 + accA1;   // V^T[f=quad*4+r][i=i0+m],    f=10 -> l
    floatx4 accB = accB0 + accB1;   // V^T[f=quad*4+r][i=i0+16+m]

    __syncthreads();   // all waves done with ring (red aliases it)
    if (quad < 3) {
        *(floatx4*)&red[((size_t)wave * IB + m) * 12 + quad * 4] = accA;
        *(floatx4*)&red[((size_t)wave * IB + 16 + m) * 12 + quad * 4] = accB;
    }
    __syncthreads();

    if (tid < IB * F) {
        const int i = tid / F;      // 0..31
        const int f = tid % F;
        float sum = 0.0f, l = 0.0f;
#pragma unroll
        for (int w = 0; w < NW; ++w) {
            sum += red[((size_t)w * IB + i) * 12 + f];
            l   += red[((size_t)w * IB + i) * 12 + 10];
        }
        out[(size_t)(i0 + i) * F + f] = sum / l;
    }
}

// ---------------------------------------------------------------------------
extern "C" void kernel_launch(void* const* d_in, const int* in_sizes, int n_in,
                              void* d_out, int out_size, void* d_ws, size_t ws_size,
                              hipStream_t stream) {
    const float* x = (const float*)d_in[0];   // [8192,3,10]
    const float* A = (const float*)d_in[1];   // [3,3]
    const float* W = (const float*)d_in[2];   // [10,10]
    float* out = (float*)d_out;               // [8192,10]

    _Float16* q_tiled = (_Float16*)d_ws;                      // 8192*16*2 = 262144 B
    _Float16* a_tiled = (_Float16*)((char*)d_ws + 262144);    // 256*512*2 = 262144 B

    pooled_kernel<<<BROWS / PB, 256, 0, stream>>>(x, A, W, q_tiled, a_tiled);
    attn_kernel<<<BROWS / IB, NW * 64, 0, stream>>>(q_tiled, a_tiled, out);
}